// Round 4
// baseline (299.289 us; speedup 1.0000x reference)
//
#include <hip/hip_runtime.h>
#include <cstdint>

// BatchInvariantAttention: B=4 H=16 S=2048 D=64, fp32 in/out, full softmax attention.
// v5: single kernel again (prep deleted — two-kernel split cost more than it saved).
// 512-thread blocks (8 waves x 32 q rows = 256 q rows/block) -> 8 blocks/bh halves
// staging redundancy; grid 64x8 = 512 = exactly 2 blocks/CU at 32KB LDS.
// Staging role-split: waves 0-3 stage K, waves 4-7 stage V (verified v2/v3 layouts,
// natural kv order). P never touches LDS: PV A-frag built in registers from the
// QK^T accumulator (layout-forced construction); V B-frag read as two ds_read_b64
// at kv=32m+4t and kv=32m+16+4t from the NATURAL-kv swizzled V^T tile, which
// realizes the same A/B pairing with no layout novelty (v4's permuted-image path
// failed on HW and is abandoned). One barrier per chunk, double-buffered K/V.

#define S_LEN 2048
#define D_DIM 64
#define BN 64
#define NCHUNK (S_LEN / BN)
#define BH 64

typedef __attribute__((ext_vector_type(8))) short bf16x8;
typedef __attribute__((ext_vector_type(4))) float f32x4;
typedef __attribute__((ext_vector_type(2))) unsigned int u32x2;

static __device__ __forceinline__ float fast_exp2(float x) {
#if __has_builtin(__builtin_amdgcn_exp2f)
    return __builtin_amdgcn_exp2f(x);
#else
    float r;
    asm volatile("v_exp_f32 %0, %1" : "=v"(r) : "v"(x));
    return r;
#endif
}

static __device__ __forceinline__ float fast_rcp(float x) {
#if __has_builtin(__builtin_amdgcn_rcpf)
    return __builtin_amdgcn_rcpf(x);
#else
    return 1.0f / x;
#endif
}

// pack two fp32 -> dword of two bf16 (a -> low half), round-half-up via +0x8000
static __device__ __forceinline__ unsigned int pack_bf16(float a, float b) {
    unsigned int ua = __builtin_bit_cast(unsigned int, a) + 0x8000u;
    unsigned int ub = __builtin_bit_cast(unsigned int, b) + 0x8000u;
    return __builtin_amdgcn_perm(ub, ua, 0x07060302u);
}

// hot path: single-instruction packed cvt (RNE). dst.lo = bf16(a), dst.hi = bf16(b)
static __device__ __forceinline__ unsigned int cvt_pk_bf16(float a, float b) {
    unsigned int r;
    asm("v_cvt_pk_bf16_f32 %0, %1, %2" : "=v"(r) : "v"(a), "v"(b));
    return r;
}

static __device__ __forceinline__ float bperm(int byte_addr, float v) {
    return __builtin_bit_cast(float,
        __builtin_amdgcn_ds_bpermute(byte_addr, __builtin_bit_cast(int, v)));
}

__global__ __launch_bounds__(512, 4)
void attn_fwd(const float* __restrict__ Qg, const float* __restrict__ Kg,
              const float* __restrict__ Vg, float* __restrict__ Og) {
    const int bh   = blockIdx.x;   // 0..63 (fastest -> XCD = bh%8, all tiles of a bh on one XCD)
    const int tile = blockIdx.y;   // 0..7
    const int tid  = threadIdx.x;  // 0..511
    const int wave = tid >> 6;     // 0..7
    const int lane = tid & 63;
    const int quad = lane >> 4;
    const int lc   = lane & 15;

    const size_t base = (size_t)bh * S_LEN * D_DIM;
    const float* Q = Qg + base;
    const float* K = Kg + base;
    const float* V = Vg + base;
    float*       O = Og + base;

    const int q0 = tile * 256 + wave * 32;   // this wave's 32 q rows

    __shared__ __align__(16) short Kb[2][64 * 64];   // [kv][d], granule ^ (kv&7) swizzle
    __shared__ __align__(16) short Vb[2][64 * 64];   // [d][kv], granule ^ (d&7)  swizzle
    // 32768 B total -> 2 blocks/CU (grid == machine capacity)

    // ---- Q fragments (B-operand: n=lc=q, k slots = quad*8+j), scale = log2(e)/8 folded in
    const float QSCALE = 1.44269504088896f / 8.0f;
    bf16x8 qf[2][2];
#pragma unroll
    for (int qb = 0; qb < 2; ++qb)
#pragma unroll
        for (int dc = 0; dc < 2; ++dc) {
            const float* src = Q + (size_t)(q0 + qb * 16 + lc) * D_DIM + dc * 32 + quad * 8;
            f32x4 a = *(const f32x4*)src;
            f32x4 b = *(const f32x4*)(src + 4);
            union { unsigned int u[4]; bf16x8 v; } cvt;
            cvt.u[0] = pack_bf16(a[0] * QSCALE, a[1] * QSCALE);
            cvt.u[1] = pack_bf16(a[2] * QSCALE, a[3] * QSCALE);
            cvt.u[2] = pack_bf16(b[0] * QSCALE, b[1] * QSCALE);
            cvt.u[3] = pack_bf16(b[2] * QSCALE, b[3] * QSCALE);
            qf[qb][dc] = cvt.v;
        }

    f32x4 oacc[2][4];   // [qb][dblk]  O accumulators (C layout: row=q=quad*4+r, col=d=lc)
#pragma unroll
    for (int qb = 0; qb < 2; ++qb)
#pragma unroll
        for (int dblk = 0; dblk < 4; ++dblk)
            oacc[qb][dblk] = (f32x4){0.f, 0.f, 0.f, 0.f};
    float lsum[2] = {0.f, 0.f};

    // ---- staging role split: waves 0-3 stage K, waves 4-7 stage V (wave-uniform branch)
    const bool doK  = (tid < 256);
    const int st_id = doK ? tid : (tid - 256);
    const int srow  = st_id >> 4;          // 0..15
    const int scol  = (st_id & 15) * 4;    // d offset 0,4,..,60
    const int sg    = scol >> 3;           // 16B granule of scol
    const int vkm   = srow * 4;            // V: kv micro-base (0,4,..,60)

    f32x4 sreg[4];                          // staging registers (one chunk in flight)
    {
        const float* p = doK ? K : V;
#pragma unroll
        for (int i = 0; i < 4; ++i) {
            const int row = doK ? (srow + i * 16) : (vkm + i);
            sreg[i] = *(const f32x4*)(p + (size_t)row * D_DIM + scol);
        }
    }

    for (int ch = 0; ch < NCHUNK; ++ch) {
        short* kb = Kb[ch & 1];
        short* vb = Vb[ch & 1];

        // ---- publish this chunk's tiles (WAR vs laggard readers of buf[(ch-1)&1] is safe:
        // they passed barrier(ch-1) only after finishing those reads; we write buf[ch&1])
        if (doK) {
#pragma unroll
            for (int i = 0; i < 4; ++i) {
                const int row = srow + i * 16;
                u32x2 w;
                w[0] = pack_bf16(sreg[i][0], sreg[i][1]);
                w[1] = pack_bf16(sreg[i][2], sreg[i][3]);
                *(u32x2*)(&kb[row * 64 + ((sg ^ (row & 7)) << 3) + (scol & 7)]) = w;
            }
        } else {
#pragma unroll
            for (int j = 0; j < 4; ++j) {   // 4x4 in-register transpose
                const int d = scol + j;
                u32x2 w;
                w[0] = pack_bf16(sreg[0][j], sreg[1][j]);
                w[1] = pack_bf16(sreg[2][j], sreg[3][j]);
                *(u32x2*)(&vb[d * 64 + (((vkm >> 3) ^ (d & 7)) << 3) + (vkm & 7)]) = w;
            }
        }

        // ---- prefetch next chunk into registers (flies across barrier + compute)
        if (ch + 1 < NCHUNK) {
            const float* p = (doK ? K : V) + (size_t)(ch + 1) * BN * D_DIM;
#pragma unroll
            for (int i = 0; i < 4; ++i) {
                const int row = doK ? (srow + i * 16) : (vkm + i);
                sreg[i] = *(const f32x4*)(p + (size_t)row * D_DIM + scol);
            }
        }

        __syncthreads();   // tiles visible to all 8 waves

        // ---- S^T = K_tile . Q^T : C frag lane holds q=lc, kv = kvf*16 + quad*4 + r
        f32x4 st[2][4];    // [qb][kvf]
        __builtin_amdgcn_s_setprio(1);
#pragma unroll
        for (int kvf = 0; kvf < 4; ++kvf) {
            const int krr = kvf * 16 + lc;
            const bf16x8 ka = *(const bf16x8*)(&kb[krr * 64 + ((quad       ^ (lc & 7)) << 3)]);
            const bf16x8 kbf = *(const bf16x8*)(&kb[krr * 64 + (((quad + 4) ^ (lc & 7)) << 3)]);
#pragma unroll
            for (int qb = 0; qb < 2; ++qb) {
                f32x4 c = {0.f, 0.f, 0.f, 0.f};
                c = __builtin_amdgcn_mfma_f32_16x16x32_bf16(ka,  qf[qb][0], c, 0, 0, 0);
                c = __builtin_amdgcn_mfma_f32_16x16x32_bf16(kbf, qf[qb][1], c, 0, 0, 0);
                st[qb][kvf] = c;
            }
        }
        __builtin_amdgcn_s_setprio(0);

        // ---- p = exp2(s); PV A-frags built IN REGISTERS.
        // Lane (q=lc, quad t) holds P[q][kv=16kvf+4t+r]. Slot j of pf[qb][m] is
        // st[qb][2m+(j>>2)][j&3]  ->  kv = 32m + 16(j>>2) + 4t + (j&3).
        bf16x8 pf[2][2];   // [qb][m]
#pragma unroll
        for (int qb = 0; qb < 2; ++qb) {
            float csum = 0.f;
            union { unsigned int u[4]; bf16x8 v; } cv[2];
#pragma unroll
            for (int kvf = 0; kvf < 4; ++kvf) {
                const float p0 = fast_exp2(st[qb][kvf][0]);
                const float p1 = fast_exp2(st[qb][kvf][1]);
                const float p2 = fast_exp2(st[qb][kvf][2]);
                const float p3 = fast_exp2(st[qb][kvf][3]);
                cv[kvf >> 1].u[(kvf & 1) * 2 + 0] = cvt_pk_bf16(p0, p1);
                cv[kvf >> 1].u[(kvf & 1) * 2 + 1] = cvt_pk_bf16(p2, p3);
                csum += (p0 + p1) + (p2 + p3);   // 3-deep tree per kvf
            }
            lsum[qb] += csum;
            pf[qb][0] = cv[0].v;
            pf[qb][1] = cv[1].v;
        }

        // ---- O += P.V : V B-frag slot j must be V[kv=32m+16(j>>2)+4t+(j&3)][d].
        // From the NATURAL-kv V^T tile that is two 4-short groups per lane:
        //   slots 0-3 <- kv0 = 32m + 4t,  slots 4-7 <- kv1 = 32m + 16 + 4t.
#pragma unroll
        for (int m = 0; m < 2; ++m) {
            bf16x8 vfm[4];
#pragma unroll
            for (int dblk = 0; dblk < 4; ++dblk) {
                const int d  = dblk * 16 + lc;
                const int g0 = (m * 4     + (quad >> 1)) ^ (d & 7);
                const int g1 = (m * 4 + 2 + (quad >> 1)) ^ (d & 7);
                const int o  = (quad & 1) << 2;
                union { unsigned long long q[2]; bf16x8 v; } uv;
                uv.q[0] = *(const unsigned long long*)(&vb[d * 64 + (g0 << 3) + o]);
                uv.q[1] = *(const unsigned long long*)(&vb[d * 64 + (g1 << 3) + o]);
                vfm[dblk] = uv.v;
            }
            __builtin_amdgcn_s_setprio(1);
#pragma unroll
            for (int dblk = 0; dblk < 4; ++dblk) {
                oacc[0][dblk] =
                    __builtin_amdgcn_mfma_f32_16x16x32_bf16(pf[0][m], vfm[dblk], oacc[0][dblk], 0, 0, 0);
                oacc[1][dblk] =
                    __builtin_amdgcn_mfma_f32_16x16x32_bf16(pf[1][m], vfm[dblk], oacc[1][dblk], 0, 0, 0);
            }
            __builtin_amdgcn_s_setprio(0);
        }
    }

    // ---- epilogue: finish row sums (reduce over quads), divide, store coalesced
#pragma unroll
    for (int qb = 0; qb < 2; ++qb) {
        float l = lsum[qb];
        l += __shfl_xor(l, 16, 64);
        l += __shfl_xor(l, 32, 64);
        float rin = fast_rcp(l);     // lane's rin is for q = qb*16 + lc
        float linv[4];
#pragma unroll
        for (int r = 0; r < 4; ++r)
            linv[r] = bperm((quad * 4 + r) << 2, rin);  // fetch rin for q = qb*16+quad*4+r
#pragma unroll
        for (int dblk = 0; dblk < 4; ++dblk)
#pragma unroll
            for (int r = 0; r < 4; ++r)
                O[(size_t)(q0 + qb * 16 + quad * 4 + r) * D_DIM + dblk * 16 + lc] =
                    oacc[qb][dblk][r] * linv[r];
    }
}

extern "C" void kernel_launch(void* const* d_in, const int* in_sizes, int n_in,
                              void* d_out, int out_size, void* d_ws, size_t ws_size,
                              hipStream_t stream) {
    const float* Q = (const float*)d_in[0];
    const float* K = (const float*)d_in[1];
    const float* V = (const float*)d_in[2];
    float* O = (float*)d_out;
    (void)in_sizes; (void)n_in; (void)out_size; (void)d_ws; (void)ws_size;

    dim3 grid(BH, 8);   // x = bh (XCD locality), y = q tile (256 rows each)
    attn_fwd<<<grid, 512, 0, stream>>>(Q, K, V, O);
}

// Round 5
// 206.637 us; speedup vs baseline: 1.4484x; 1.4484x over previous
//
#include <hip/hip_runtime.h>
#include <cstdint>

// BatchInvariantAttention: B=4 H=16 S=2048 D=64, fp32 in/out, full softmax attention.
// v6 = baseline shell (single kernel, 256 thr, grid 64x16, two barriers/chunk,
// reg-staged K/V -> LDS, proven 127us & spill-free) + ONE structural delta:
// the P LDS round-trip is deleted. PV A-frag is built IN REGISTERS from the QK^T
// accumulator (v5-proven), V B-frag read as two ds_read_b64 from the natural-kv
// swizzled V^T tile (v5-proven pairing). K tile uses the v5-proven 64-pitch XOR
// swizzle (conflict-free b128 reads, 16KB LDS total, single-buffered).
// Micro-wins kept from v3: v_cvt_pk_bf16_f32 hot pack, tree lsum, s_setprio.

#define S_LEN 2048
#define D_DIM 64
#define BN 64
#define NCHUNK (S_LEN / BN)
#define BH 64

typedef __attribute__((ext_vector_type(8))) short bf16x8;
typedef __attribute__((ext_vector_type(4))) float f32x4;
typedef __attribute__((ext_vector_type(2))) unsigned int u32x2;

static __device__ __forceinline__ float fast_exp2(float x) {
#if __has_builtin(__builtin_amdgcn_exp2f)
    return __builtin_amdgcn_exp2f(x);
#else
    float r;
    asm volatile("v_exp_f32 %0, %1" : "=v"(r) : "v"(x));
    return r;
#endif
}

static __device__ __forceinline__ float fast_rcp(float x) {
#if __has_builtin(__builtin_amdgcn_rcpf)
    return __builtin_amdgcn_rcpf(x);
#else
    return 1.0f / x;
#endif
}

// pack two fp32 -> dword of two bf16 (a -> low half), round-half-up via +0x8000
static __device__ __forceinline__ unsigned int pack_bf16(float a, float b) {
    unsigned int ua = __builtin_bit_cast(unsigned int, a) + 0x8000u;
    unsigned int ub = __builtin_bit_cast(unsigned int, b) + 0x8000u;
    return __builtin_amdgcn_perm(ub, ua, 0x07060302u);
}

// hot path: single-instruction packed cvt (RNE). dst.lo = bf16(a), dst.hi = bf16(b)
static __device__ __forceinline__ unsigned int cvt_pk_bf16(float a, float b) {
    unsigned int r;
    asm("v_cvt_pk_bf16_f32 %0, %1, %2" : "=v"(r) : "v"(a), "v"(b));
    return r;
}

static __device__ __forceinline__ float bperm(int byte_addr, float v) {
    return __builtin_bit_cast(float,
        __builtin_amdgcn_ds_bpermute(byte_addr, __builtin_bit_cast(int, v)));
}

__global__ __launch_bounds__(256, 4)
void attn_fwd(const float* __restrict__ Qg, const float* __restrict__ Kg,
              const float* __restrict__ Vg, float* __restrict__ Og) {
    const int bh   = blockIdx.x;   // 0..63 (fastest -> XCD = bh%8, L2 locality)
    const int tile = blockIdx.y;   // 0..15
    const int tid  = threadIdx.x;
    const int wave = tid >> 6;
    const int lane = tid & 63;
    const int quad = lane >> 4;
    const int lc   = lane & 15;

    const size_t base = (size_t)bh * S_LEN * D_DIM;
    const float* Q = Qg + base;
    const float* K = Kg + base;
    const float* V = Vg + base;
    float*       O = Og + base;

    const int q0 = tile * 128 + wave * 32;   // this wave's 32 q rows

    __shared__ __align__(16) short Kb[64 * 64];   // [kv][d], granule ^ (kv&7) swizzle (8 KB)
    __shared__ __align__(16) short Vt[64 * 64];   // [d][kv], granule ^ (d&7)  swizzle (8 KB)
    // 16384 B total -> LDS is nowhere near limiting 4 blocks/CU

    // ---- Q fragments (B-operand: n=lc=q, k slots = quad*8+j), scale = log2(e)/8 folded in
    const float QSCALE = 1.44269504088896f / 8.0f;
    bf16x8 qf[2][2];
#pragma unroll
    for (int qb = 0; qb < 2; ++qb)
#pragma unroll
        for (int dc = 0; dc < 2; ++dc) {
            const float* src = Q + (size_t)(q0 + qb * 16 + lc) * D_DIM + dc * 32 + quad * 8;
            f32x4 a = *(const f32x4*)src;
            f32x4 b = *(const f32x4*)(src + 4);
            union { unsigned int u[4]; bf16x8 v; } cvt;
            cvt.u[0] = pack_bf16(a[0] * QSCALE, a[1] * QSCALE);
            cvt.u[1] = pack_bf16(a[2] * QSCALE, a[3] * QSCALE);
            cvt.u[2] = pack_bf16(b[0] * QSCALE, b[1] * QSCALE);
            cvt.u[3] = pack_bf16(b[2] * QSCALE, b[3] * QSCALE);
            qf[qb][dc] = cvt.v;
        }

    f32x4 oacc[2][4];   // [qb][dblk]  O accumulators (C layout: row=q=quad*4+r, col=d=lc)
#pragma unroll
    for (int qb = 0; qb < 2; ++qb)
#pragma unroll
        for (int dblk = 0; dblk < 4; ++dblk)
            oacc[qb][dblk] = (f32x4){0.f, 0.f, 0.f, 0.f};
    float lsum[2] = {0.f, 0.f};

    // staging addressing (each thread stages 4 K row-quarters + a 4x4 V micro-tile)
    const int krow = tid >> 4;           // 0..15
    const int kcol = (tid & 15) * 4;     // d offset 0,4,..,60
    const int gk   = kcol >> 3;          // 16B granule of kcol
    const int vkm  = (tid >> 4) * 4;     // kv micro-base for V transpose
    const float* kptr = K + (size_t)krow * D_DIM + kcol;
    const float* vptr = V + (size_t)vkm * D_DIM + kcol;

    for (int ch = 0; ch < NCHUNK; ++ch) {
        // global loads first (in flight across the barrier)
        f32x4 kreg[4], vreg[4];
#pragma unroll
        for (int i = 0; i < 4; ++i) kreg[i] = *(const f32x4*)(kptr + (size_t)i * 16 * D_DIM);
#pragma unroll
        for (int i = 0; i < 4; ++i) vreg[i] = *(const f32x4*)(vptr + (size_t)i * D_DIM);
        kptr += BN * D_DIM;
        vptr += BN * D_DIM;

        __syncthreads();   // previous chunk's LDS reads done
#pragma unroll
        for (int i = 0; i < 4; ++i) {
            const int row = krow + i * 16;
            u32x2 w;
            w[0] = pack_bf16(kreg[i][0], kreg[i][1]);
            w[1] = pack_bf16(kreg[i][2], kreg[i][3]);
            *(u32x2*)(&Kb[row * 64 + ((gk ^ (row & 7)) << 3) + (kcol & 7)]) = w;
        }
#pragma unroll
        for (int j = 0; j < 4; ++j) {   // 4x4 in-register transpose of V micro-tile
            const int d = kcol + j;
            u32x2 w;
            w[0] = pack_bf16(vreg[0][j], vreg[1][j]);
            w[1] = pack_bf16(vreg[2][j], vreg[3][j]);
            *(u32x2*)(&Vt[d * 64 + (((vkm >> 3) ^ (d & 7)) << 3) + (vkm & 7)]) = w;
        }
        __syncthreads();   // LDS ready

        // ---- S^T = K_tile . Q^T : C frag lane holds q=lc, kv = kvf*16 + quad*4 + r
        f32x4 st[2][4];    // [qb][kvf]
        __builtin_amdgcn_s_setprio(1);
#pragma unroll
        for (int kvf = 0; kvf < 4; ++kvf) {
            const int krr = kvf * 16 + lc;
            const bf16x8 ka = *(const bf16x8*)(&Kb[krr * 64 + ((quad       ^ (lc & 7)) << 3)]);
            const bf16x8 kb = *(const bf16x8*)(&Kb[krr * 64 + (((quad + 4) ^ (lc & 7)) << 3)]);
#pragma unroll
            for (int qb = 0; qb < 2; ++qb) {
                f32x4 c = {0.f, 0.f, 0.f, 0.f};
                c = __builtin_amdgcn_mfma_f32_16x16x32_bf16(ka, qf[qb][0], c, 0, 0, 0);
                c = __builtin_amdgcn_mfma_f32_16x16x32_bf16(kb, qf[qb][1], c, 0, 0, 0);
                st[qb][kvf] = c;
            }
        }
        __builtin_amdgcn_s_setprio(0);

        // ---- p = exp2(s); PV A-frags built IN REGISTERS (v5-proven).
        // Lane (q=lc, quad t) holds P[q][kv=16kvf+4t+r]. Slot j of pf[qb][m] is
        // st[qb][2m+(j>>2)][j&3]  ->  kv = 32m + 16(j>>2) + 4t + (j&3).
        bf16x8 pf[2][2];   // [qb][m]
#pragma unroll
        for (int qb = 0; qb < 2; ++qb) {
            float csum = 0.f;
            union { unsigned int u[4]; bf16x8 v; } cv[2];
#pragma unroll
            for (int kvf = 0; kvf < 4; ++kvf) {
                const float p0 = fast_exp2(st[qb][kvf][0]);
                const float p1 = fast_exp2(st[qb][kvf][1]);
                const float p2 = fast_exp2(st[qb][kvf][2]);
                const float p3 = fast_exp2(st[qb][kvf][3]);
                cv[kvf >> 1].u[(kvf & 1) * 2 + 0] = cvt_pk_bf16(p0, p1);
                cv[kvf >> 1].u[(kvf & 1) * 2 + 1] = cvt_pk_bf16(p2, p3);
                csum += (p0 + p1) + (p2 + p3);   // 3-deep tree per kvf
            }
            lsum[qb] += csum;
            pf[qb][0] = cv[0].v;
            pf[qb][1] = cv[1].v;
        }

        // ---- O += P.V : V B-frag slot j must be V[kv=32m+16(j>>2)+4t+(j&3)][d].
        // Natural-kv V^T tile -> two b64 groups per lane (v5-proven):
        //   slots 0-3 <- kv0 = 32m + 4t,  slots 4-7 <- kv1 = 32m + 16 + 4t.
#pragma unroll
        for (int m = 0; m < 2; ++m) {
            bf16x8 vfm[4];
#pragma unroll
            for (int dblk = 0; dblk < 4; ++dblk) {
                const int d  = dblk * 16 + lc;
                const int g0 = (m * 4     + (quad >> 1)) ^ (d & 7);
                const int g1 = (m * 4 + 2 + (quad >> 1)) ^ (d & 7);
                const int o  = (quad & 1) << 2;
                union { unsigned long long q[2]; bf16x8 v; } uv;
                uv.q[0] = *(const unsigned long long*)(&Vt[d * 64 + (g0 << 3) + o]);
                uv.q[1] = *(const unsigned long long*)(&Vt[d * 64 + (g1 << 3) + o]);
                vfm[dblk] = uv.v;
            }
            __builtin_amdgcn_s_setprio(1);
#pragma unroll
            for (int dblk = 0; dblk < 4; ++dblk) {
                oacc[0][dblk] =
                    __builtin_amdgcn_mfma_f32_16x16x32_bf16(pf[0][m], vfm[dblk], oacc[0][dblk], 0, 0, 0);
                oacc[1][dblk] =
                    __builtin_amdgcn_mfma_f32_16x16x32_bf16(pf[1][m], vfm[dblk], oacc[1][dblk], 0, 0, 0);
            }
            __builtin_amdgcn_s_setprio(0);
        }
    }

    // ---- epilogue: finish row sums (reduce over quads), divide, store coalesced
#pragma unroll
    for (int qb = 0; qb < 2; ++qb) {
        float l = lsum[qb];
        l += __shfl_xor(l, 16, 64);
        l += __shfl_xor(l, 32, 64);
        float rin = fast_rcp(l);     // lane's rin is for q = qb*16 + lc
        float linv[4];
#pragma unroll
        for (int r = 0; r < 4; ++r)
            linv[r] = bperm((quad * 4 + r) << 2, rin);  // fetch rin for q = qb*16+quad*4+r
#pragma unroll
        for (int dblk = 0; dblk < 4; ++dblk)
#pragma unroll
            for (int r = 0; r < 4; ++r)
                O[(size_t)(q0 + qb * 16 + quad * 4 + r) * D_DIM + dblk * 16 + lc] =
                    oacc[qb][dblk][r] * linv[r];
    }
}

extern "C" void kernel_launch(void* const* d_in, const int* in_sizes, int n_in,
                              void* d_out, int out_size, void* d_ws, size_t ws_size,
                              hipStream_t stream) {
    const float* Q = (const float*)d_in[0];
    const float* K = (const float*)d_in[1];
    const float* V = (const float*)d_in[2];
    float* O = (float*)d_out;
    (void)in_sizes; (void)n_in; (void)out_size; (void)d_ws; (void)ws_size;

    dim3 grid(BH, 16);   // x = bh (XCD locality), y = q tile
    attn_fwd<<<grid, 256, 0, stream>>>(Q, K, V, O);
}

// Round 6
// 184.414 us; speedup vs baseline: 1.6229x; 1.1205x over previous
//
#include <hip/hip_runtime.h>
#include <cstdint>

// BatchInvariantAttention: B=4 H=16 S=2048 D=64, fp32 in/out, full softmax attention.
// v7 = v6 (in-register P, b64 V-frag reads, XOR-swizzled K/V tiles — all HW-proven)
// with three ratio/VALU levers:
//  - 64 q rows per wave (qb=0..3), grid 64x8, __launch_bounds__(256,2) [256-VGPR
//    budget -- v5's spill was the (512,4)=64-VGPR cap, not the structure]:
//    staging cost per unit of work HALVES, MFMA:VALU ratio up.
//  - double-buffered K/V LDS (32KB) -> ONE barrier per chunk (v3-proven pattern),
//    next-chunk globals prefetched before the barrier (latency under compute).
//  - v_cvt_pk_bf16_f32 staging packs (1 op vs 3).
//  - row-sum via MFMA with all-ones B: every lane gets lsum(q) in oacc's layout;
//    all lsum VALU adds AND the epilogue shfl/bperm redistribution deleted.

#define S_LEN 2048
#define D_DIM 64
#define BN 64
#define NCHUNK (S_LEN / BN)
#define BH 64

typedef __attribute__((ext_vector_type(8))) short bf16x8;
typedef __attribute__((ext_vector_type(4))) float f32x4;
typedef __attribute__((ext_vector_type(2))) unsigned int u32x2;

static __device__ __forceinline__ float fast_exp2(float x) {
#if __has_builtin(__builtin_amdgcn_exp2f)
    return __builtin_amdgcn_exp2f(x);
#else
    float r;
    asm volatile("v_exp_f32 %0, %1" : "=v"(r) : "v"(x));
    return r;
#endif
}

static __device__ __forceinline__ float fast_rcp(float x) {
#if __has_builtin(__builtin_amdgcn_rcpf)
    return __builtin_amdgcn_rcpf(x);
#else
    return 1.0f / x;
#endif
}

// single-instruction packed cvt (RNE). dst.lo = bf16(a), dst.hi = bf16(b)
static __device__ __forceinline__ unsigned int cvt_pk_bf16(float a, float b) {
    unsigned int r;
    asm("v_cvt_pk_bf16_f32 %0, %1, %2" : "=v"(r) : "v"(a), "v"(b));
    return r;
}

__global__ __launch_bounds__(256, 2)
void attn_fwd(const float* __restrict__ Qg, const float* __restrict__ Kg,
              const float* __restrict__ Vg, float* __restrict__ Og) {
    const int bh   = blockIdx.x;   // 0..63 (fastest -> XCD = bh%8; same-bh blocks share XCD)
    const int tile = blockIdx.y;   // 0..7
    const int tid  = threadIdx.x;
    const int wave = tid >> 6;
    const int lane = tid & 63;
    const int quad = lane >> 4;
    const int lc   = lane & 15;

    const size_t base = (size_t)bh * S_LEN * D_DIM;
    const float* Q = Qg + base;
    const float* K = Kg + base;
    const float* V = Vg + base;
    float*       O = Og + base;

    const int q0 = tile * 256 + wave * 64;   // this wave's 64 q rows

    __shared__ __align__(16) short Kb[2][64 * 64];   // [kv][d], granule ^ (kv&7) swizzle
    __shared__ __align__(16) short Vt[2][64 * 64];   // [d][kv], granule ^ (d&7)  swizzle
    // 32768 B total; 2 blocks/CU -> 64KB/CU, not limiting

    // ---- Q fragments (B-operand: n=lc=q, k slots = quad*8+j), scale = log2(e)/8 folded in
    const float QSCALE = 1.44269504088896f / 8.0f;
    bf16x8 qf[4][2];
#pragma unroll
    for (int qb = 0; qb < 4; ++qb)
#pragma unroll
        for (int dc = 0; dc < 2; ++dc) {
            const float* src = Q + (size_t)(q0 + qb * 16 + lc) * D_DIM + dc * 32 + quad * 8;
            f32x4 a = *(const f32x4*)src;
            f32x4 b = *(const f32x4*)(src + 4);
            union { unsigned int u[4]; bf16x8 v; } cvt;
            cvt.u[0] = cvt_pk_bf16(a[0] * QSCALE, a[1] * QSCALE);
            cvt.u[1] = cvt_pk_bf16(a[2] * QSCALE, a[3] * QSCALE);
            cvt.u[2] = cvt_pk_bf16(b[0] * QSCALE, b[1] * QSCALE);
            cvt.u[3] = cvt_pk_bf16(b[2] * QSCALE, b[3] * QSCALE);
            qf[qb][dc] = cvt.v;
        }

    // all-ones bf16 B-fragment for the row-sum MFMA (B all-ones -> every output
    // column j holds sum_k A[i][k]: each lane gets lsum for rows quad*4+r)
    bf16x8 ones;
    {
        union { unsigned int u[4]; bf16x8 v; } cv;
#pragma unroll
        for (int i = 0; i < 4; ++i) cv.u[i] = 0x3F803F80u;
        ones = cv.v;
    }

    f32x4 oacc[4][4];   // [qb][dblk]  O accumulators (C layout: row=q=quad*4+r, col=d=lc)
    f32x4 lacc[4];      // [qb]        row-sum accumulators (same row layout, any col)
#pragma unroll
    for (int qb = 0; qb < 4; ++qb) {
        lacc[qb] = (f32x4){0.f, 0.f, 0.f, 0.f};
#pragma unroll
        for (int dblk = 0; dblk < 4; ++dblk)
            oacc[qb][dblk] = (f32x4){0.f, 0.f, 0.f, 0.f};
    }

    // staging addressing (each thread stages 4 K row-quarters + a 4x4 V micro-tile)
    const int krow = tid >> 4;           // 0..15
    const int kcol = (tid & 15) * 4;     // d offset 0,4,..,60
    const int gk   = kcol >> 3;          // 16B granule of kcol
    const int vkm  = (tid >> 4) * 4;     // kv micro-base for V transpose
    const float* kptr = K + (size_t)krow * D_DIM + kcol;
    const float* vptr = V + (size_t)vkm * D_DIM + kcol;

    // prologue: chunk 0 globals in flight
    f32x4 kreg[4], vreg[4];
#pragma unroll
    for (int i = 0; i < 4; ++i) kreg[i] = *(const f32x4*)(kptr + (size_t)i * 16 * D_DIM);
#pragma unroll
    for (int i = 0; i < 4; ++i) vreg[i] = *(const f32x4*)(vptr + (size_t)i * D_DIM);
    kptr += BN * D_DIM;
    vptr += BN * D_DIM;

#pragma unroll 1
    for (int ch = 0; ch < NCHUNK; ++ch) {
        short* kb = Kb[ch & 1];
        short* vb = Vt[ch & 1];

        // ---- publish this chunk (writes to buf[ch&1]; all waves' reads of this
        // buffer finished before the PREVIOUS barrier -> WAR-safe with 1 barrier)
#pragma unroll
        for (int i = 0; i < 4; ++i) {
            const int row = krow + i * 16;
            u32x2 w;
            w[0] = cvt_pk_bf16(kreg[i][0], kreg[i][1]);
            w[1] = cvt_pk_bf16(kreg[i][2], kreg[i][3]);
            *(u32x2*)(&kb[row * 64 + ((gk ^ (row & 7)) << 3) + (kcol & 7)]) = w;
        }
#pragma unroll
        for (int j = 0; j < 4; ++j) {   // 4x4 in-register transpose of V micro-tile
            const int d = kcol + j;
            u32x2 w;
            w[0] = cvt_pk_bf16(vreg[0][j], vreg[1][j]);
            w[1] = cvt_pk_bf16(vreg[2][j], vreg[3][j]);
            *(u32x2*)(&vb[d * 64 + (((vkm >> 3) ^ (d & 7)) << 3) + (vkm & 7)]) = w;
        }

        // ---- prefetch next chunk's globals (in flight across barrier + compute)
        if (ch + 1 < NCHUNK) {
#pragma unroll
            for (int i = 0; i < 4; ++i) kreg[i] = *(const f32x4*)(kptr + (size_t)i * 16 * D_DIM);
#pragma unroll
            for (int i = 0; i < 4; ++i) vreg[i] = *(const f32x4*)(vptr + (size_t)i * D_DIM);
            kptr += BN * D_DIM;
            vptr += BN * D_DIM;
        }

        __syncthreads();   // tiles visible to all waves (one barrier per chunk)

        // ---- S^T = K_tile . Q^T : C frag lane holds q=lc, kv = kvf*16 + quad*4 + r
        f32x4 st[4][4];    // [qb][kvf]
        __builtin_amdgcn_s_setprio(1);
#pragma unroll
        for (int kvf = 0; kvf < 4; ++kvf) {
            const int krr = kvf * 16 + lc;
            const bf16x8 ka  = *(const bf16x8*)(&kb[krr * 64 + ((quad       ^ (lc & 7)) << 3)]);
            const bf16x8 kb2 = *(const bf16x8*)(&kb[krr * 64 + (((quad + 4) ^ (lc & 7)) << 3)]);
#pragma unroll
            for (int qb = 0; qb < 4; ++qb) {
                f32x4 c = {0.f, 0.f, 0.f, 0.f};
                c = __builtin_amdgcn_mfma_f32_16x16x32_bf16(ka,  qf[qb][0], c, 0, 0, 0);
                c = __builtin_amdgcn_mfma_f32_16x16x32_bf16(kb2, qf[qb][1], c, 0, 0, 0);
                st[qb][kvf] = c;
            }
        }
        __builtin_amdgcn_s_setprio(0);

        // ---- p = exp2(s); PV A-frags built IN REGISTERS (HW-proven layout).
        // Lane (q=lc, quad t) holds P[q][kv=16kvf+4t+r]. Slot j of pf[qb][m] is
        // st[qb][2m+(j>>2)][j&3]  ->  kv = 32m + 16(j>>2) + 4t + (j&3).
        bf16x8 pf[4][2];   // [qb][m]
#pragma unroll
        for (int qb = 0; qb < 4; ++qb) {
            union { unsigned int u[4]; bf16x8 v; } cv[2];
#pragma unroll
            for (int kvf = 0; kvf < 4; ++kvf) {
                const float p0 = fast_exp2(st[qb][kvf][0]);
                const float p1 = fast_exp2(st[qb][kvf][1]);
                const float p2 = fast_exp2(st[qb][kvf][2]);
                const float p3 = fast_exp2(st[qb][kvf][3]);
                cv[kvf >> 1].u[(kvf & 1) * 2 + 0] = cvt_pk_bf16(p0, p1);
                cv[kvf >> 1].u[(kvf & 1) * 2 + 1] = cvt_pk_bf16(p2, p3);
            }
            pf[qb][0] = cv[0].v;
            pf[qb][1] = cv[1].v;
        }

        // ---- O += P.V ; lsum += P.ones : V B-frag slot j = V[kv=32m+16(j>>2)+4t+(j&3)][d]
        // natural-kv V^T tile -> two b64 groups per lane (HW-proven pairing)
#pragma unroll
        for (int m = 0; m < 2; ++m) {
            bf16x8 vfm[4];
#pragma unroll
            for (int dblk = 0; dblk < 4; ++dblk) {
                const int d  = dblk * 16 + lc;
                const int g0 = (m * 4     + (quad >> 1)) ^ (d & 7);
                const int g1 = (m * 4 + 2 + (quad >> 1)) ^ (d & 7);
                const int o  = (quad & 1) << 2;
                union { unsigned long long q[2]; bf16x8 v; } uv;
                uv.q[0] = *(const unsigned long long*)(&vb[d * 64 + (g0 << 3) + o]);
                uv.q[1] = *(const unsigned long long*)(&vb[d * 64 + (g1 << 3) + o]);
                vfm[dblk] = uv.v;
            }
            __builtin_amdgcn_s_setprio(1);
#pragma unroll
            for (int dblk = 0; dblk < 4; ++dblk) {
#pragma unroll
                for (int qb = 0; qb < 4; ++qb)
                    oacc[qb][dblk] =
                        __builtin_amdgcn_mfma_f32_16x16x32_bf16(pf[qb][m], vfm[dblk], oacc[qb][dblk], 0, 0, 0);
            }
#pragma unroll
            for (int qb = 0; qb < 4; ++qb)
                lacc[qb] =
                    __builtin_amdgcn_mfma_f32_16x16x32_bf16(pf[qb][m], ones, lacc[qb], 0, 0, 0);
            __builtin_amdgcn_s_setprio(0);
        }
    }

    // ---- epilogue: lacc already holds row sums in oacc's row layout -> just divide
#pragma unroll
    for (int qb = 0; qb < 4; ++qb) {
        float linv[4];
#pragma unroll
        for (int r = 0; r < 4; ++r) linv[r] = fast_rcp(lacc[qb][r]);
#pragma unroll
        for (int dblk = 0; dblk < 4; ++dblk)
#pragma unroll
            for (int r = 0; r < 4; ++r)
                O[(size_t)(q0 + qb * 16 + quad * 4 + r) * D_DIM + dblk * 16 + lc] =
                    oacc[qb][dblk][r] * linv[r];
    }
}

extern "C" void kernel_launch(void* const* d_in, const int* in_sizes, int n_in,
                              void* d_out, int out_size, void* d_ws, size_t ws_size,
                              hipStream_t stream) {
    const float* Q = (const float*)d_in[0];
    const float* K = (const float*)d_in[1];
    const float* V = (const float*)d_in[2];
    float* O = (float*)d_out;
    (void)in_sizes; (void)n_in; (void)out_size; (void)d_ws; (void)ws_size;

    dim3 grid(BH, 8);   // x = bh (XCD locality), y = q tile (256 rows each)
    attn_fwd<<<grid, 256, 0, stream>>>(Q, K, V, O);
}